// Round 6
// baseline (929.577 us; speedup 1.0000x reference)
//
#include <hip/hip_runtime.h>

// ---------------------------------------------------------------------------
// ModifiedTransformerEncoderLayer on MI355X (gfx950)
// B=4096 J=17 D=512 H=8 DK=64, M=B*J=69632. I/O f32; compute bf16 MFMA.
//
// Round 10 (this round):
//  (1) prep_transpose rewritten as LDS-tiled 64x64 transpose (old version
//      read Wo/Wg at 2KB stride per lane -> ~84MB effective scattered
//      traffic for 5MB of weights).
//  (2) O-projection GEMM fused with residual+LN1 (gemm_ln): tile 128 rows x
//      512 cols (full N), BK=32, 8 waves (wave w owns cols 64w..64w+63),
//      triple-buffered LDS + counted vmcnt(5) (round-5-proven structure).
//      Epilogue: v = acc + bo + src; cross-wave row stats via LDS partials;
//      writes X bf16 directly. Eliminates ln_res kernel + ATT buffer
//      round trip (142MB).
//  QKV/GCN GEMMs keep the 8-phase 256x256 schedule (measured 27.7% MfmaUtil
//  ~= the MFMA-issue floor at 19.4cyc/SIMD per 16x16x32; K=512 limits
//  further pipelining gains).
//
// ws layout:
//   WT1 @0x000000  WT2 @0x180000  WT3 @0x200000  smalls @0x300000
//   SRCB @0x0400000 ; QKV @0x4800000 ; O @0x0400000 (SRCB dead)
//   X @0x8C00000 ; H01 @0x0400000 (O dead)
// ---------------------------------------------------------------------------

typedef __attribute__((ext_vector_type(4))) float floatx4;
typedef __attribute__((ext_vector_type(8))) short short8;

#define AS1 __attribute__((address_space(1)))
#define AS3 __attribute__((address_space(3)))

__device__ __forceinline__ float bf2f(unsigned short u) {
  union { unsigned int i; float f; } x;
  x.i = ((unsigned int)u) << 16;
  return x.f;
}

__device__ __forceinline__ unsigned short f2bf(float f) {
  union { float f; unsigned int i; } x;
  x.f = f;
  unsigned int r = x.i + 0x7fffu + ((x.i >> 16) & 1u);  // RNE
  return (unsigned short)(r >> 16);
}

__device__ __forceinline__ void unpack8(uint4 u, float* f) {
  unsigned int uu[4] = {u.x, u.y, u.z, u.w};
#pragma unroll
  for (int i = 0; i < 4; ++i) {
    f[2 * i]     = bf2f((unsigned short)(uu[i] & 0xffffu));
    f[2 * i + 1] = bf2f((unsigned short)(uu[i] >> 16));
  }
}

__device__ __forceinline__ uint4 pack8(const float* f) {
  unsigned int uu[4];
#pragma unroll
  for (int i = 0; i < 4; ++i)
    uu[i] = (unsigned int)f2bf(f[2 * i]) | ((unsigned int)f2bf(f[2 * i + 1]) << 16);
  uint4 u; u.x = uu[0]; u.y = uu[1]; u.z = uu[2]; u.w = uu[3];
  return u;
}

__device__ __forceinline__ float wave_sum(float v) {
#pragma unroll
  for (int m = 1; m < 64; m <<= 1) v += __shfl_xor(v, m, 64);
  return v;
}

// async global->LDS, 16B/lane; LDS dest = wave-uniform base + lane*16
__device__ __forceinline__ void gload_lds16(const unsigned short* g, AS3 char* l) {
  __builtin_amdgcn_global_load_lds((const AS1 void*)g, (AS3 void*)l, 16, 0, 0);
}

// ---------------------------------------------------------------------------
// src f32 -> bf16, 8 elems/thread
// ---------------------------------------------------------------------------
__global__ __launch_bounds__(256) void convert_src(
    const float* __restrict__ in, unsigned short* __restrict__ out) {
  const size_t i = ((size_t)blockIdx.x * 256 + threadIdx.x) * 8;
  const float4 a = *(const float4*)(in + i);
  const float4 b = *(const float4*)(in + i + 4);
  const float f[8] = {a.x, a.y, a.z, a.w, b.x, b.y, b.z, b.w};
  *(uint4*)(out + i) = pack8(f);
}

// ---------------------------------------------------------------------------
// 8-phase 256x256 GEMM helpers (QKV / GCN GEMMs)
// ---------------------------------------------------------------------------
__device__ __forceinline__ void stgA(const unsigned short* a0, size_t gTh,
                                     AS3 char* L, int ldsW, int bb, int kt,
                                     int kh) {
  gload_lds16(a0 + gTh + kt * 64 + kh * 32,
              L + bb * 32768 + kh * 16384 + ldsW);
  gload_lds16(a0 + gTh + 65536 + kt * 64 + kh * 32,
              L + bb * 32768 + kh * 16384 + 8192 + ldsW);
}
__device__ __forceinline__ void stgB(const unsigned short* b0, size_t gTh,
                                     AS3 char* L, int ldsW, int bb, int kt,
                                     int kh) {
  gload_lds16(b0 + gTh + kt * 64 + kh * 32,
              L + 65536 + bb * 32768 + kh * 16384 + ldsW);
  gload_lds16(b0 + gTh + 65536 + kt * 64 + kh * 32,
              L + 65536 + bb * 32768 + kh * 16384 + 8192 + ldsW);
}

template <int BB>
__device__ __forceinline__ void kt_step(
    int kt, const char* Lr, AS3 char* L,
    const unsigned short* a0, const unsigned short* b0, size_t gTh, int ldsW,
    int aBase, int bBase, floatx4 (&acc)[8][4]) {
  constexpr int base = BB * 32768;
  short8 afL[4], afH[4], bf[4];

  // ph0
#pragma unroll
  for (int i = 0; i < 4; ++i)
    afL[i] = *(const short8*)(Lr + base + aBase + i * 1024);
#pragma unroll
  for (int j = 0; j < 4; ++j)
    bf[j] = *(const short8*)(Lr + base + bBase + j * 1024);
  if (kt < 7) stgA(a0, gTh, L, ldsW, BB ^ 1, kt + 1, 1);
  __builtin_amdgcn_s_barrier();
  asm volatile("s_waitcnt lgkmcnt(0)" ::: "memory");
  __builtin_amdgcn_sched_barrier(0);
  __builtin_amdgcn_s_setprio(1);
#pragma unroll
  for (int i = 0; i < 4; ++i)
#pragma unroll
    for (int j = 0; j < 4; ++j)
      acc[i][j] = __builtin_amdgcn_mfma_f32_16x16x32_bf16(afL[i], bf[j], acc[i][j], 0, 0, 0);
  __builtin_amdgcn_s_setprio(0);
  __builtin_amdgcn_s_barrier();

  // ph1
#pragma unroll
  for (int i = 0; i < 4; ++i)
    afH[i] = *(const short8*)(Lr + base + aBase + 4096 + i * 1024);
  if (kt < 7) stgB(b0, gTh, L, ldsW, BB ^ 1, kt + 1, 1);
  __builtin_amdgcn_s_barrier();
  asm volatile("s_waitcnt lgkmcnt(0)" ::: "memory");
  __builtin_amdgcn_sched_barrier(0);
  __builtin_amdgcn_s_setprio(1);
#pragma unroll
  for (int i = 0; i < 4; ++i)
#pragma unroll
    for (int j = 0; j < 4; ++j)
      acc[4 + i][j] = __builtin_amdgcn_mfma_f32_16x16x32_bf16(afH[i], bf[j], acc[4 + i][j], 0, 0, 0);
  __builtin_amdgcn_s_setprio(0);
  if (kt < 7) asm volatile("s_waitcnt vmcnt(8)" ::: "memory");
  else        asm volatile("s_waitcnt vmcnt(0)" ::: "memory");
  __builtin_amdgcn_sched_barrier(0);
  __builtin_amdgcn_s_barrier();

  // ph2
#pragma unroll
  for (int i = 0; i < 4; ++i)
    afL[i] = *(const short8*)(Lr + base + 16384 + aBase + i * 1024);
#pragma unroll
  for (int j = 0; j < 4; ++j)
    bf[j] = *(const short8*)(Lr + base + 16384 + bBase + j * 1024);
  if (kt < 6) stgA(a0, gTh, L, ldsW, BB, kt + 2, 0);
  __builtin_amdgcn_s_barrier();
  asm volatile("s_waitcnt lgkmcnt(0)" ::: "memory");
  __builtin_amdgcn_sched_barrier(0);
  __builtin_amdgcn_s_setprio(1);
#pragma unroll
  for (int i = 0; i < 4; ++i)
#pragma unroll
    for (int j = 0; j < 4; ++j)
      acc[i][j] = __builtin_amdgcn_mfma_f32_16x16x32_bf16(afL[i], bf[j], acc[i][j], 0, 0, 0);
  __builtin_amdgcn_s_setprio(0);
  __builtin_amdgcn_s_barrier();

  // ph3
#pragma unroll
  for (int i = 0; i < 4; ++i)
    afH[i] = *(const short8*)(Lr + base + 16384 + aBase + 4096 + i * 1024);
  if (kt < 6) stgB(b0, gTh, L, ldsW, BB, kt + 2, 0);
  __builtin_amdgcn_s_barrier();
  asm volatile("s_waitcnt lgkmcnt(0)" ::: "memory");
  __builtin_amdgcn_sched_barrier(0);
  __builtin_amdgcn_s_setprio(1);
#pragma unroll
  for (int i = 0; i < 4; ++i)
#pragma unroll
    for (int j = 0; j < 4; ++j)
      acc[4 + i][j] = __builtin_amdgcn_mfma_f32_16x16x32_bf16(afH[i], bf[j], acc[4 + i][j], 0, 0, 0);
  __builtin_amdgcn_s_setprio(0);
  if (kt < 6)       asm volatile("s_waitcnt vmcnt(8)" ::: "memory");
  else if (kt == 6) asm volatile("s_waitcnt vmcnt(4)" ::: "memory");
  __builtin_amdgcn_sched_barrier(0);
  __builtin_amdgcn_s_barrier();
}

// ---------------------------------------------------------------------------
// GEMM: C[M,N] = A[M,512] @ BT[N,512]^T (+ bias[N]), bf16 in/out, f32 accum.
// 256x256 tile, BK=64, 8-phase. Grid 1-D = (M/256)*(N/256), %8==0.
// ---------------------------------------------------------------------------
__global__ __launch_bounds__(512, 2) void gemm_bt(
    const unsigned short* __restrict__ A,
    const unsigned short* __restrict__ BT,
    const float* __restrict__ bias,
    unsigned short* __restrict__ C, int N) {
  __shared__ char LDSR[131072];
  const int t = threadIdx.x;
  const int wave = t >> 6, lane = t & 63;
  const int wm = wave >> 2, wn = wave & 3;
  const int e = lane & 15, g = lane >> 4;

  const int nTN = N >> 8;
  const int q8 = gridDim.x >> 3;
  const int lin = ((int)blockIdx.x & 7) * q8 + ((int)blockIdx.x >> 3);
  const int tm = lin / nTN;
  const int tn = lin - tm * nTN;
  const long rowBase = (long)tm * 256;
  const long colBase = (long)tn * 256;

  const unsigned short* a0 = A + (size_t)rowBase * 512;
  const unsigned short* b0 = BT + (size_t)colBase * 512;

  const size_t gTh = (size_t)(t >> 2) * 512 +
                     (size_t)(((t & 3) ^ ((t >> 3) & 3))) * 8;
  AS3 char* L = (AS3 char*)LDSR;
  const int ldsW = wave * 1024;

  const int swz16 = ((g ^ ((e >> 1) & 3)) << 4);
  const char* Lr = LDSR;
  const int aBase = wm * 8192 + e * 64 + swz16;
  const int bBase = 65536 + wn * 4096 + e * 64 + swz16;

  floatx4 acc[8][4];
#pragma unroll
  for (int i = 0; i < 8; ++i)
#pragma unroll
    for (int j = 0; j < 4; ++j) acc[i][j] = (floatx4){0.f, 0.f, 0.f, 0.f};

  stgA(a0, gTh, L, ldsW, 0, 0, 0); stgB(b0, gTh, L, ldsW, 0, 0, 0);
  stgA(a0, gTh, L, ldsW, 0, 0, 1); stgB(b0, gTh, L, ldsW, 0, 0, 1);
  stgA(a0, gTh, L, ldsW, 1, 1, 0); stgB(b0, gTh, L, ldsW, 1, 1, 0);
  asm volatile("s_waitcnt vmcnt(8)" ::: "memory");
  __builtin_amdgcn_sched_barrier(0);
  __builtin_amdgcn_s_barrier();

#pragma unroll 1
  for (int ktp = 0; ktp < 4; ++ktp) {
    kt_step<0>(2 * ktp,     Lr, L, a0, b0, gTh, ldsW, aBase, bBase, acc);
    kt_step<1>(2 * ktp + 1, Lr, L, a0, b0, gTh, ldsW, aBase, bBase, acc);
  }

  asm volatile("s_waitcnt vmcnt(0) lgkmcnt(0)" ::: "memory");
  __builtin_amdgcn_sched_barrier(0);

  const int q4 = g << 2;
#pragma unroll
  for (int mf = 0; mf < 8; ++mf) {
    const long rowa = rowBase + wm * 128 + mf * 16 + q4;
#pragma unroll
    for (int nf = 0; nf < 4; ++nf) {
      const long col = colBase + wn * 64 + nf * 16 + e;
      const float badd = bias ? bias[col] : 0.f;
#pragma unroll
      for (int r = 0; r < 4; ++r)
        C[(size_t)(rowa + r) * N + col] = f2bf(acc[mf][nf][r] + badd);
    }
  }
}

// ---------------------------------------------------------------------------
// Fused O-projection GEMM + bias + residual + LN1 -> X bf16.
// X[M,512] = LN1(src + O[M,512] @ WT2[512,512]^T + bo).
// Tile 128 rows x 512 cols (full N), BK=32, 16 kt, 8 waves (wave w = cols
// 64w..64w+63), triple-buffered LDS + counted vmcnt(5). Grid = 544 (%8==0).
// ---------------------------------------------------------------------------
__global__ __launch_bounds__(512) void gemm_ln(
    const unsigned short* __restrict__ A,   // O bf16 [M,512]
    const unsigned short* __restrict__ BT,  // WT2 [512,512]
    const float* __restrict__ bias,         // bo
    const float* __restrict__ srcf,         // src f32 [M,512]
    const float* __restrict__ g1, const float* __restrict__ b1,
    unsigned short* __restrict__ X) {
  __shared__ char LDSR[122880];  // 3 buf x (A 8KB + B 32KB)
  const int t = threadIdx.x;
  const int w = t >> 6, lane = t & 63;
  const int e = lane & 15, g = lane >> 4;

  const int q8 = gridDim.x >> 3;
  const int tm = ((int)blockIdx.x & 7) * q8 + ((int)blockIdx.x >> 3);
  const long rowBase = (long)tm * 128;
  const unsigned short* a0 = A + (size_t)rowBase * 512;

  // staging: A chunks c=t (512); B chunks c=t+512i (2048). inverse swizzle.
  const size_t gOffA = (size_t)(t >> 2) * 512 +
                       (size_t)(((t & 3) ^ ((t >> 3) & 3))) * 8;
  size_t gOffB[4];
#pragma unroll
  for (int i = 0; i < 4; ++i) {
    const int c = t + 512 * i;
    gOffB[i] = (size_t)(c >> 2) * 512 + (size_t)(((c & 3) ^ ((c >> 3) & 3))) * 8;
  }
  AS3 char* L = (AS3 char*)LDSR;
  const int ldsW = w * 1024;

#define STG5(bb, kt)                                                         \
  do {                                                                       \
    gload_lds16(a0 + gOffA + (kt) * 32, L + (bb) * 40960 + ldsW);            \
    gload_lds16(BT + gOffB[0] + (kt) * 32, L + (bb) * 40960 + 8192 + ldsW);  \
    gload_lds16(BT + gOffB[1] + (kt) * 32,                                   \
                L + (bb) * 40960 + 16384 + ldsW);                            \
    gload_lds16(BT + gOffB[2] + (kt) * 32,                                   \
                L + (bb) * 40960 + 24576 + ldsW);                            \
    gload_lds16(BT + gOffB[3] + (kt) * 32,                                   \
                L + (bb) * 40960 + 32768 + ldsW);                            \
  } while (0)

  const int swz16 = ((g ^ ((e >> 1) & 3)) << 4);
  const char* Lr = LDSR;

  floatx4 acc[8][4];
#pragma unroll
  for (int i = 0; i < 8; ++i)
#pragma unroll
    for (int j = 0; j < 4; ++j) acc[i][j] = (floatx4){0.f, 0.f, 0.f, 0.f};

  STG5(0, 0);
  STG5(1, 1);
  asm volatile("s_waitcnt vmcnt(5)" ::: "memory");
  __builtin_amdgcn_sched_barrier(0);
  __builtin_amdgcn_s_barrier();

#pragma unroll 1
  for (int kt = 0; kt < 16; ++kt) {
    const int bb = kt % 3;
    if (kt + 2 < 16) STG5((kt + 2) % 3, kt + 2);

    const int base = bb * 40960;
    short8 af[8], bf4[4];
#pragma unroll
    for (int mf = 0; mf < 8; ++mf)
      af[mf] = *(const short8*)(Lr + base + (16 * mf + e) * 64 + swz16);
#pragma unroll
    for (int nf = 0; nf < 4; ++nf)
      bf4[nf] = *(const short8*)(Lr + base + 8192 +
                                 (64 * w + 16 * nf + e) * 64 + swz16);
#pragma unroll
    for (int mf = 0; mf < 8; ++mf)
#pragma unroll
      for (int nf = 0; nf < 4; ++nf)
        acc[mf][nf] = __builtin_amdgcn_mfma_f32_16x16x32_bf16(af[mf], bf4[nf], acc[mf][nf], 0, 0, 0);

    if (kt == 15) break;
    if (kt < 14) asm volatile("s_waitcnt vmcnt(5)" ::: "memory");
    else         asm volatile("s_waitcnt vmcnt(0)" ::: "memory");
    __builtin_amdgcn_sched_barrier(0);
    __builtin_amdgcn_s_barrier();
  }
#undef STG5
  __syncthreads();  // LDS reuse for LN reductions

  // ---- epilogue: v = acc + bias + src; row stats; LN; write X ----
  float bb4[4], gg4[4], be4[4];
#pragma unroll
  for (int nf = 0; nf < 4; ++nf) {
    const int col = 64 * w + 16 * nf + e;
    bb4[nf] = bias[col];
    gg4[nf] = g1[col];
    be4[nf] = b1[col];
  }
#pragma unroll
  for (int mf = 0; mf < 8; ++mf)
#pragma unroll
    for (int r = 0; r < 4; ++r) {
      const long row = rowBase + 16 * mf + 4 * g + r;
#pragma unroll
      for (int nf = 0; nf < 4; ++nf)
        acc[mf][nf][r] += bb4[nf] + srcf[(size_t)row * 512 + 64 * w + 16 * nf + e];
    }

  // per-row partial sums over this wave's 64 cols (reduce over e-lanes)
  float* Ps  = (float*)LDSR;            // [128][9]
  float* Ps2 = (float*)(LDSR + 4608);   // [128][9]
#pragma unroll
  for (int mf = 0; mf < 8; ++mf)
#pragma unroll
    for (int r = 0; r < 4; ++r) {
      float s = 0.f, s2 = 0.f;
#pragma unroll
      for (int nf = 0; nf < 4; ++nf) {
        const float v = acc[mf][nf][r];
        s += v; s2 += v * v;
      }
#pragma unroll
      for (int m = 1; m < 16; m <<= 1) {
        s  += __shfl_xor(s,  m, 64);
        s2 += __shfl_xor(s2, m, 64);
      }
      if (e == 0) {
        const int rl = 16 * mf + 4 * g + r;
        Ps[rl * 9 + w]  = s;
        Ps2[rl * 9 + w] = s2;
      }
    }
  __syncthreads();

  float* St = (float*)(LDSR + 9216);  // mean[128] @0, rs[128] @128
  if (t < 128) {
    float s = 0.f, s2 = 0.f;
#pragma unroll
    for (int ww = 0; ww < 8; ++ww) { s += Ps[t * 9 + ww]; s2 += Ps2[t * 9 + ww]; }
    const float mean = s * (1.f / 512.f);
    const float var = s2 * (1.f / 512.f) - mean * mean;
    St[t] = mean;
    St[128 + t] = rsqrtf(var + 1e-5f);
  }
  __syncthreads();

#pragma unroll
  for (int mf = 0; mf < 8; ++mf)
#pragma unroll
    for (int r = 0; r < 4; ++r) {
      const int rl = 16 * mf + 4 * g + r;
      const float mean = St[rl];
      const float rs = St[128 + rl];
      const long row = rowBase + rl;
#pragma unroll
      for (int nf = 0; nf < 4; ++nf) {
        const int col = 64 * w + 16 * nf + e;
        X[(size_t)row * 512 + col] =
            f2bf((acc[mf][nf][r] - mean) * rs * gg4[nf] + be4[nf]);
      }
    }
}

// ---------------------------------------------------------------------------
// MFMA attention: one wave per (b,h). grid = 8192 blocks x 256 thr (4 waves).
// ---------------------------------------------------------------------------
__global__ __launch_bounds__(256) void attn_kernel(
    const unsigned short* __restrict__ qkv, unsigned short* __restrict__ o) {
  __shared__ unsigned short Vl[4][17][76];
  const int t = threadIdx.x;
  const int wave = t >> 6, lane = t & 63;
  const int wid = blockIdx.x * 4 + wave;
  const int b = wid >> 3, h = wid & 7;
  const int e = lane & 15, g = lane >> 4;

  const unsigned short* base = qkv + (size_t)b * 17 * 1536 + h * 64;

  unsigned short (*V)[76] = Vl[wave];
  for (int c = lane; c < 136; c += 64) {
    const int kk = c >> 3, e0 = (c & 7) << 3;
    const uint4 u = *(const uint4*)(base + (size_t)kk * 1536 + 1024 + e0);
    *(uint2*)&V[kk][e0]     = make_uint2(u.x, u.y);
    *(uint2*)&V[kk][e0 + 4] = make_uint2(u.z, u.w);
  }

  const int ko = g << 3;
  const unsigned short* qrow  = base + (size_t)e * 1536;
  const unsigned short* row16 = base + (size_t)16 * 1536;
  const short8 Q0  = *(const short8*)(qrow + ko);
  const short8 Q1  = *(const short8*)(qrow + 32 + ko);
  const short8 K0  = *(const short8*)(qrow + 512 + ko);
  const short8 K1  = *(const short8*)(qrow + 512 + 32 + ko);
  const short8 Qb0 = *(const short8*)(row16 + ko);
  const short8 Qb1 = *(const short8*)(row16 + 32 + ko);
  const short8 Kb0 = *(const short8*)(row16 + 512 + ko);
  const short8 Kb1 = *(const short8*)(row16 + 512 + 32 + ko);

  floatx4 sT[2][2];
#pragma unroll
  for (int i = 0; i < 2; ++i)
#pragma unroll
    for (int j = 0; j < 2; ++j) sT[i][j] = (floatx4){0.f, 0.f, 0.f, 0.f};
  sT[0][0] = __builtin_amdgcn_mfma_f32_16x16x32_bf16(K0, Q0, sT[0][0], 0, 0, 0);
  sT[0][0] = __builtin_amdgcn_mfma_f32_16x16x32_bf16(K1, Q1, sT[0][0], 0, 0, 0);
  sT[0][1] = __builtin_amdgcn_mfma_f32_16x16x32_bf16(K0, Qb0, sT[0][1], 0, 0, 0);
  sT[0][1] = __builtin_amdgcn_mfma_f32_16x16x32_bf16(K1, Qb1, sT[0][1], 0, 0, 0);
  sT[1][0] = __builtin_amdgcn_mfma_f32_16x16x32_bf16(Kb0, Q0, sT[1][0], 0, 0, 0);
  sT[1][0] = __builtin_amdgcn_mfma_f32_16x16x32_bf16(Kb1, Q1, sT[1][0], 0, 0, 0);
  sT[1][1] = __builtin_amdgcn_mfma_f32_16x16x32_bf16(Kb0, Qb0, sT[1][1], 0, 0, 0);
  sT[1][1] = __builtin_amdgcn_mfma_f32_16x16x32_bf16(Kb1, Qb1, sT[1][1], 0, 0, 0);

  short8 PA[2];
#pragma unroll
  for (int ni = 0; ni < 2; ++ni) {
    float v[4];
#pragma unroll
    for (int r = 0; r < 4; ++r) v[r] = sT[0][ni][r] * 0.125f;
    const float v16 = sT[1][ni][0] * 0.125f;
    float m = fmaxf(fmaxf(v[0], v[1]), fmaxf(v[2], v[3]));
    if (g == 0) m = fmaxf(m, v16);
    m = fmaxf(m, __shfl_xor(m, 16, 64));
    m = fmaxf(m, __shfl_xor(m, 32, 64));
    float p[4], sum = 0.f;
#pragma unroll
    for (int r = 0; r < 4; ++r) { p[r] = __expf(v[r] - m); sum += p[r]; }
    float p16 = (g == 0) ? __expf(v16 - m) : 0.f;
    sum += p16;
    sum += __shfl_xor(sum, 16, 64);
    sum += __shfl_xor(sum, 32, 64);
    const float inv = 1.f / sum;
#pragma unroll
    for (int r = 0; r < 4; ++r) p[r] *= inv;
    p16 *= inv;

    const unsigned int lo = (unsigned int)f2bf(p[0]) | ((unsigned int)f2bf(p[1]) << 16);
    const unsigned int hi = (unsigned int)f2bf(p[2]) | ((unsigned int)f2bf(p[3]) << 16);
    const unsigned int w16 = (unsigned int)f2bf(p16);

    const int colsrc = ni ? 0 : e;
    const int s0 = colsrc + ((g & 1) << 5);
    unsigned int w0 = __shfl(lo, s0, 64);
    unsigned int w1 = __shfl(hi, s0, 64);
    unsigned int w2 = __shfl(lo, s0 + 16, 64);
    unsigned int w3 = __shfl(hi, s0 + 16, 64);
    const unsigned int a16 = __shfl(w16, colsrc, 64);
    if (g == 2) { w0 = a16; w1 = 0; w2 = 0; w3 = 0; }
    if (g == 3) { w0 = 0; w1 = 0; w2 = 0; w3 = 0; }
    union { unsigned int u[4]; short8 s; } fa;
    fa.u[0] = w0; fa.u[1] = w1; fa.u[2] = w2; fa.u[3] = w3;
    PA[ni] = fa.s;
  }

  floatx4 o0[4], o1[4];
#pragma unroll
  for (int tt = 0; tt < 4; ++tt) {
    o0[tt] = (floatx4){0.f, 0.f, 0.f, 0.f};
    o1[tt] = (floatx4){0.f, 0.f, 0.f, 0.f};
  }
#pragma unroll
  for (int tt = 0; tt < 4; ++tt) {
    const int c = tt * 16 + e;
    union { unsigned int u[4]; short8 s; } fb;
#pragma unroll
    for (int i = 0; i < 4; ++i) {
      int ka = (g << 3) + 2 * i;
      int kb = ka + 1;
      if (ka > 16) ka = 16;
      if (kb > 16) kb = 16;
      fb.u[i] = (unsigned int)V[ka][c] | ((unsigned int)V[kb][c] << 16);
    }
    o0[tt] = __builtin_amdgcn_mfma_f32_16x16x32_bf16(PA[0], fb.s, o0[tt], 0, 0, 0);
    o1[tt] = __builtin_amdgcn_mfma_f32_16x16x32_bf16(PA[1], fb.s, o1[tt], 0, 0, 0);
  }

  unsigned short* ob = o + (size_t)b * 17 * 512 + h * 64;
#pragma unroll
  for (int tt = 0; tt < 4; ++tt)
#pragma unroll
    for (int r = 0; r < 4; ++r)
      ob[(size_t)(4 * g + r) * 512 + tt * 16 + e] = f2bf(o0[tt][r]);
  if (g == 0) {
#pragma unroll
    for (int tt = 0; tt < 4; ++tt)
      ob[(size_t)16 * 512 + tt * 16 + e] = f2bf(o1[tt][0]);
  }
}

// ---------------------------------------------------------------------------
// out_f32 = LN2(x + gcn + b_gcn); gcn = Adiag[j]*h0[row] + sum_nbr w*h1[b,k]
// ---------------------------------------------------------------------------
__global__ __launch_bounds__(256) void gcn_ln_kernel(
    const unsigned short* __restrict__ x, const unsigned short* __restrict__ h01,
    const float* __restrict__ Adiag, const int* __restrict__ cnt,
    const int* __restrict__ nbrk, const float* __restrict__ nbrw,
    const float* __restrict__ bgcn,
    const float* __restrict__ g, const float* __restrict__ beta,
    float* __restrict__ out) {
  const long row = (long)blockIdx.x * 4 + (threadIdx.x >> 6);
  const int lane = threadIdx.x & 63;
  const int b = (int)(row / 17);
  const int j = (int)(row - (long)b * 17);
  const int d0 = lane * 8;

  float accv[8];
  {
    const float w = Adiag[j];
    float f[8];
    unpack8(*(const uint4*)(h01 + (size_t)row * 1024 + d0), f);
#pragma unroll
    for (int i = 0; i < 8; ++i) accv[i] = w * f[i];
  }
  const int c = cnt[j];
  for (int nb = 0; nb < c; ++nb) {
    const int kk = nbrk[j * 8 + nb];
    const float w = nbrw[j * 8 + nb];
    float f[8];
    unpack8(*(const uint4*)(h01 + ((size_t)b * 17 + kk) * 1024 + 512 + d0), f);
#pragma unroll
    for (int i = 0; i < 8; ++i) accv[i] += w * f[i];
  }

  float fx[8], vals[8];
  unpack8(*(const uint4*)(x + (size_t)row * 512 + d0), fx);
  const float4 bg0 = *(const float4*)(bgcn + d0);
  const float4 bg1 = *(const float4*)(bgcn + d0 + 4);
  const float fbg[8] = {bg0.x, bg0.y, bg0.z, bg0.w, bg1.x, bg1.y, bg1.z, bg1.w};
  float s = 0.f, s2 = 0.f;
#pragma unroll
  for (int i = 0; i < 8; ++i) {
    vals[i] = fx[i] + accv[i] + fbg[i];
    s += vals[i];
    s2 += vals[i] * vals[i];
  }
  const float mean = wave_sum(s) * (1.f / 512.f);
  const float var = wave_sum(s2) * (1.f / 512.f) - mean * mean;
  const float rs = rsqrtf(var + 1e-5f);

  const float4 g0 = *(const float4*)(g + d0);
  const float4 g1 = *(const float4*)(g + d0 + 4);
  const float4 bb0 = *(const float4*)(beta + d0);
  const float4 bb1 = *(const float4*)(beta + d0 + 4);
  const float fg[8]  = {g0.x, g0.y, g0.z, g0.w, g1.x, g1.y, g1.z, g1.w};
  const float fbt[8] = {bb0.x, bb0.y, bb0.z, bb0.w, bb1.x, bb1.y, bb1.z, bb1.w};
  float4 y0, y1;
  y0.x = (vals[0] - mean) * rs * fg[0] + fbt[0];
  y0.y = (vals[1] - mean) * rs * fg[1] + fbt[1];
  y0.z = (vals[2] - mean) * rs * fg[2] + fbt[2];
  y0.w = (vals[3] - mean) * rs * fg[3] + fbt[3];
  y1.x = (vals[4] - mean) * rs * fg[4] + fbt[4];
  y1.y = (vals[5] - mean) * rs * fg[5] + fbt[5];
  y1.z = (vals[6] - mean) * rs * fg[6] + fbt[6];
  y1.w = (vals[7] - mean) * rs * fg[7] + fbt[7];
  *(float4*)(out + (size_t)row * 512 + d0) = y0;
  *(float4*)(out + (size_t)row * 512 + d0 + 4) = y1;
}

// ---------------------------------------------------------------------------
// Weight transposes via LDS 64x64 tiles (coalesced both sides).
// grid = 384: [0,192) WT1; [192,256) WT2; [256,384) WT3.
// ---------------------------------------------------------------------------
__global__ __launch_bounds__(256) void prep_transpose(
    const float* __restrict__ Wq, const float* __restrict__ Wk,
    const float* __restrict__ Wv, const float* __restrict__ Wo,
    const float* __restrict__ Wg,
    unsigned short* __restrict__ WT1, unsigned short* __restrict__ WT2,
    unsigned short* __restrict__ WT3) {
  __shared__ float T[64][65];
  const int t = threadIdx.x;
  const int bid = blockIdx.x;

  const float* srcP;
  int strideK, kBase, dstRowBase;
  unsigned short* dst;
  if (bid < 192) {          // WT1: per (which,hh) 512k x 64e, 8 k-tiles
    const int u = bid >> 3, kt8 = bid & 7;
    const int which = u >> 3, hh = u & 7;
    const float* W = (which == 0) ? Wq : (which == 1) ? Wk : Wv;
    srcP = W + hh * 32768 + kt8 * 64 * 64;
    strideK = 64;
    kBase = kt8 * 64;
    dstRowBase = which * 512 + hh * 64;
    dst = WT1;
  } else if (bid < 256) {   // WT2: Wo 512k x 512n
    const int t2 = bid - 192;
    const int nt = t2 >> 3, kt8 = t2 & 7;
    srcP = Wo + (size_t)kt8 * 64 * 512 + nt * 64;
    strideK = 512;
    kBase = kt8 * 64;
    dstRowBase = nt * 64;
    dst = WT2;
  } else {                  // WT3: Wg[which] 512k x 512n
    const int t3 = bid - 256;
    const int which = t3 >> 6, r = t3 & 63;
    const int nt = r >> 3, kt8 = r & 7;
    srcP = Wg + (size_t)which * 262144 + (size_t)kt8 * 64 * 512 + nt * 64;
    strideK = 512;
    kBase = kt8 * 64;
    dstRowBase = which * 512 + nt * 64;
    dst = WT3;
  }

  const int r4 = t >> 6, cl = t & 63;
#pragma unroll
  for (int p = 0; p < 16; ++p) {
    const int kl = p * 4 + r4;
    T[kl][cl] = srcP[(size_t)kl * strideK + cl];
  }
  __syncthreads();
#pragma unroll
  for (int p = 0; p < 16; ++p) {
    const int c2 = p * 4 + r4;   // output row (n-dim)
    const int k2 = cl;           // output col (k-dim)
    dst[(size_t)(dstRowBase + c2) * 512 + kBase + k2] = f2bf(T[k2][c2]);
  }
}

// ---------------------------------------------------------------------------
// bias concat (f32) + adjacency row-softmax + neighbor lists
// ---------------------------------------------------------------------------
__global__ __launch_bounds__(256) void prep_small(
    const float* __restrict__ bq, const float* __restrict__ bk,
    const float* __restrict__ bv, const float* __restrict__ bo,
    const float* __restrict__ e, const int* __restrict__ rows,
    const int* __restrict__ cols, int nnz,
    float* __restrict__ bias1, float* __restrict__ bias2,
    float* __restrict__ Adiag, int* __restrict__ cnt,
    int* __restrict__ nbrk, float* __restrict__ nbrw) {
  const int t = threadIdx.x;
  for (int i = t; i < 1536; i += 256)
    bias1[i] = (i < 512) ? bq[i] : (i < 1024) ? bk[i - 512] : bv[i - 1024];
  for (int i = t; i < 512; i += 256) bias2[i] = bo[i];
  if (t < 17) {
    float m = -1e30f;
    for (int i = 0; i < nnz; ++i)
      if (rows[i] == t) m = fmaxf(m, e[i]);
    float s = 0.f;
    for (int i = 0; i < nnz; ++i)
      if (rows[i] == t) s += __expf(e[i] - m);
    const float inv = 1.f / s;
    int c = 0;
    for (int i = 0; i < nnz; ++i)
      if (rows[i] == t) {
        const float w = __expf(e[i] - m) * inv;
        const int kk = cols[i];
        if (kk == t) Adiag[t] = w;
        else { nbrk[t * 8 + c] = kk; nbrw[t * 8 + c] = w; ++c; }
      }
    cnt[t] = c;
  }
}

// ---------------------------------------------------------------------------
extern "C" void kernel_launch(void* const* d_in, const int* in_sizes, int n_in,
                              void* d_out, int out_size, void* d_ws, size_t ws_size,
                              hipStream_t stream) {
  const float* src = (const float*)d_in[0];
  const float* Wq  = (const float*)d_in[1];
  const float* bq  = (const float*)d_in[2];
  const float* Wk  = (const float*)d_in[3];
  const float* bk  = (const float*)d_in[4];
  const float* Wv  = (const float*)d_in[5];
  const float* bv  = (const float*)d_in[6];
  const float* Wo  = (const float*)d_in[7];
  const float* bo  = (const float*)d_in[8];
  const float* ln1g = (const float*)d_in[9];
  const float* ln1b = (const float*)d_in[10];
  const float* Wg  = (const float*)d_in[11];
  const float* eg  = (const float*)d_in[12];
  const float* bg  = (const float*)d_in[13];
  const float* ln2g = (const float*)d_in[14];
  const float* ln2b = (const float*)d_in[15];
  const int* mrows = (const int*)d_in[16];
  const int* mcols = (const int*)d_in[17];
  const int nnz = in_sizes[16];

  float* out = (float*)d_out;
  char* ws = (char*)d_ws;

  unsigned short* WT1 = (unsigned short*)(ws + 0x0000000);
  unsigned short* WT2 = (unsigned short*)(ws + 0x0180000);
  unsigned short* WT3 = (unsigned short*)(ws + 0x0200000);
  float* bias1 = (float*)(ws + 0x0300000);
  float* bias2 = (float*)(ws + 0x0302000);
  float* Adiag = (float*)(ws + 0x0303000);
  int* cnt     = (int*)(ws + 0x0303100);
  int* nbrk    = (int*)(ws + 0x0303200);
  float* nbrw  = (float*)(ws + 0x0303600);
  unsigned short* SRCB = (unsigned short*)(ws + 0x0400000);
  unsigned short* QKV  = (unsigned short*)(ws + 0x4800000);
  unsigned short* O    = (unsigned short*)(ws + 0x0400000);  // after SRCB dead
  unsigned short* X    = (unsigned short*)(ws + 0x8C00000);
  unsigned short* H01  = (unsigned short*)(ws + 0x0400000);  // after O dead

  (void)n_in; (void)out_size; (void)ws_size;

  convert_src<<<17408, 256, 0, stream>>>(src, SRCB);
  prep_transpose<<<384, 256, 0, stream>>>(Wq, Wk, Wv, Wo, Wg, WT1, WT2, WT3);
  prep_small<<<1, 256, 0, stream>>>(bq, bk, bv, bo, eg, mrows, mcols, nnz,
                                    bias1, bias2, Adiag, cnt, nbrk, nbrw);
  gemm_bt<<<1632, 512, 0, stream>>>(SRCB, WT1, bias1, QKV, 1536);
  attn_kernel<<<8192, 256, 0, stream>>>(QKV, O);
  gemm_ln<<<544, 512, 0, stream>>>(O, WT2, bias2, src, ln1g, ln1b, X);
  gemm_bt<<<1088, 512, 0, stream>>>(X, WT3, nullptr, H01, 1024);
  gcn_ln_kernel<<<17408, 256, 0, stream>>>(X, H01, Adiag, cnt, nbrk, nbrw, bg,
                                           ln2g, ln2b, out);
}